// Round 12
// baseline (360.027 us; speedup 1.0000x reference)
//
#include <hip/hip_runtime.h>

#define SEQ 288
#define INP 7
#define HID 128
#define TLEN 288
#define OUTD 3
#define XW (SEQ * INP)   // 2016

typedef _Float16 f16x8 __attribute__((ext_vector_type(8)));
typedef float f32x4 __attribute__((ext_vector_type(4)));

#define NLOG2E  (-1.4426950408889634f)   // -log2(e)
#define N2LOG2E (-2.8853900817779268f)   // -2*log2(e)

__device__ __forceinline__ float exp2_fast(float x) {
#if __has_builtin(__builtin_amdgcn_exp2f)
    return __builtin_amdgcn_exp2f(x);
#else
    return __expf(x * 0.69314718056f);
#endif
}
__device__ __forceinline__ float sig2(float zp) {   // sigmoid, z pre-scaled by -log2e
    return __builtin_amdgcn_rcpf(1.0f + exp2_fast(zp));
}
__device__ __forceinline__ float tanh2(float zp) {  // tanh, z pre-scaled by -2log2e
    return 2.0f * __builtin_amdgcn_rcpf(1.0f + exp2_fast(zp)) - 1.0f;
}

// DPP-based full-wave (64) sum -> uniform scalar.
template<int CTRL, int RM>
__device__ __forceinline__ float dpp_add(float v) {
    int t = __builtin_amdgcn_update_dpp(0, __float_as_int(v), CTRL, RM, 0xF, true);
    return v + __int_as_float(t);
}
__device__ __forceinline__ float wave_sum(float v) {
    v = dpp_add<0xB1, 0xF>(v);
    v = dpp_add<0x4E, 0xF>(v);
    v = dpp_add<0x124, 0xF>(v);
    v = dpp_add<0x128, 0xF>(v);
    v = dpp_add<0x142, 0xA>(v);
    v = dpp_add<0x143, 0xC>(v);
    return __int_as_float(__builtin_amdgcn_readlane(__float_as_int(v), 63));
}

__global__ __launch_bounds__(512, 2)
void enc_dec_kernel(const float* __restrict__ x,
                    const float* __restrict__ eWih, const float* __restrict__ eWhh,
                    const float* __restrict__ ebih, const float* __restrict__ ebhh,
                    const float* __restrict__ dWih, const float* __restrict__ dWhh,
                    const float* __restrict__ dbih, const float* __restrict__ dbhh,
                    const float* __restrict__ oW,  const float* __restrict__ ob,
                    float* __restrict__ out)
{
    // Two independent 2-batch groups (A: b0-1, B: b2-3), each with its own
    // h double-buffer [dbuf][kc(4)][b(2)][ke(40 pad)] f16 (flat-indexed).
    __shared__ __align__(16) _Float16 hbA[2 * 4 * 2 * 40];
    __shared__ __align__(16) _Float16 hbB[2 * 4 * 2 * 40];
    // pre-converted x + constant-1 (bias rider): [t][gb(4)][8], j=7 == 1.0
    __shared__ __align__(16) _Float16 xf16[SEQ + 1][4][8];
    __shared__ float zbl[4][4][HID];   // decoder zbase handoff [gate][gb][u] (SCALED)
    __shared__ float cl[4][HID];       // c_enc handoff [gb][u]

    const int tid  = threadIdx.x;
    const int wave = tid >> 6;
    const int lane = tid & 63;
    const int col  = lane & 15;        // A-row source / B n-col index
    const int grp  = lane >> 4;        // A k-chunk 0..3
    const int G    = lane >> 5;        // this lane's GROUP (0=A, 1=B)
    const int bl   = (lane >> 4) & 1;  // local batch within group
    const int gb   = G * 2 + bl;       // global batch 0..3
    const int u    = wave * 16 + col;  // this lane's unit column
    const int b0   = blockIdx.x * 4;
    const bool m1  = bl != 0;
    const bool mG  = G != 0;

    // hbuf strides (f16 units): dbuf 320, kc 80, b 40
    const int rbase = (col & 1) * 40 + grp * 8;          // read offset within dbuf+kc
    const int woff  = (u >> 5) * 80 + bl * 40 + (u & 31); // write offset within dbuf
    _Float16* hbase = G ? hbB : hbA;                      // this lane writes its group

    const float GS[4] = {NLOG2E, NLOG2E, N2LOG2E, NLOG2E};

    // ---- prologue ----
    for (int i = tid; i < 2 * 4 * 2 * 40; i += 512) { hbA[i] = (_Float16)0.f; hbB[i] = (_Float16)0.f; }
    if (tid < 32) (&xf16[SEQ][0][0])[tid] = (_Float16)0.f;
    for (int i = tid; i < 4 * XW; i += 512) {
        int b = i / XW, r = i % XW;
        int t = r / INP, j = r % INP;
        xf16[t][b][j] = (_Float16)x[(size_t)(b0 + b) * XW + r];
    }
    for (int i = tid; i < SEQ * 4; i += 512)
        xf16[i >> 2][i & 3][7] = (_Float16)1.0f;

    // ---- encoder weights as persistent B-fragments (PRE-SCALED, shared A/B) ----
    f16x8 wfrag[4][5];
    #pragma unroll
    for (int gt = 0; gt < 4; ++gt) {
        const int row = gt * HID + u;
        const float gs = GS[gt];
        #pragma unroll
        for (int kc = 0; kc < 4; ++kc) {
            const float* wr = eWhh + (size_t)row * HID + kc * 32 + grp * 8;
            f16x8 wf;
            #pragma unroll
            for (int e = 0; e < 8; ++e) wf[e] = (_Float16)(gs * wr[e]);
            wfrag[gt][kc] = wf;
        }
        {
            f16x8 wf;
            #pragma unroll
            for (int e = 0; e < 8; ++e) {
                int j = grp * 8 + e;
                float v = 0.f;
                if (j < INP)       v = eWih[(size_t)row * INP + j];
                else if (j == 7)   v = ebih[row] + ebhh[row];
                wf[e] = (_Float16)(gs * v);
            }
            wfrag[gt][4] = wf;
        }
    }

    __syncthreads();

    float cc = 0.f;
    const f32x4 zero = (f32x4){0.f, 0.f, 0.f, 0.f};

    f32x4 accXA[4], accXB[4];
    {
        f16x8 axA = *(const f16x8*)&xf16[0][col & 1][0];
        f16x8 axB = *(const f16x8*)&xf16[0][2 + (col & 1)][0];
        #pragma unroll
        for (int gt = 0; gt < 4; ++gt) {
            accXA[gt] = __builtin_amdgcn_mfma_f32_16x16x32_f16(axA, wfrag[gt][4], zero, 0, 0, 0);
            accXB[gt] = __builtin_amdgcn_mfma_f32_16x16x32_f16(axB, wfrag[gt][4], zero, 0, 0, 0);
        }
    }

    // ---------------- encoder: 288 steps, dual-pipe, unrolled x2 ----------------
    #define ENC_STEP(T, CUR, NXT)                                                      \
    {                                                                                  \
        f16x8 aA0 = *(const f16x8*)&hbA[(CUR)*320 + 0*80 + rbase];                     \
        f16x8 aB0 = *(const f16x8*)&hbB[(CUR)*320 + 0*80 + rbase];                     \
        f16x8 aA1 = *(const f16x8*)&hbA[(CUR)*320 + 1*80 + rbase];                     \
        f16x8 aB1 = *(const f16x8*)&hbB[(CUR)*320 + 1*80 + rbase];                     \
        f16x8 aA2 = *(const f16x8*)&hbA[(CUR)*320 + 2*80 + rbase];                     \
        f16x8 aB2 = *(const f16x8*)&hbB[(CUR)*320 + 2*80 + rbase];                     \
        f16x8 aA3 = *(const f16x8*)&hbA[(CUR)*320 + 3*80 + rbase];                     \
        f16x8 aB3 = *(const f16x8*)&hbB[(CUR)*320 + 3*80 + rbase];                     \
        f32x4 accA[4], accB[4];                                                        \
        _Pragma("unroll")                                                              \
        for (int gt = 0; gt < 4; ++gt) {                                               \
            accA[gt] = __builtin_amdgcn_mfma_f32_16x16x32_f16(aA0, wfrag[gt][0], accXA[gt], 0, 0, 0); \
            accB[gt] = __builtin_amdgcn_mfma_f32_16x16x32_f16(aB0, wfrag[gt][0], accXB[gt], 0, 0, 0); \
        }                                                                              \
        _Pragma("unroll")                                                              \
        for (int gt = 0; gt < 4; ++gt) {                                               \
            accA[gt] = __builtin_amdgcn_mfma_f32_16x16x32_f16(aA1, wfrag[gt][1], accA[gt], 0, 0, 0);  \
            accB[gt] = __builtin_amdgcn_mfma_f32_16x16x32_f16(aB1, wfrag[gt][1], accB[gt], 0, 0, 0);  \
        }                                                                              \
        _Pragma("unroll")                                                              \
        for (int gt = 0; gt < 4; ++gt) {                                               \
            accA[gt] = __builtin_amdgcn_mfma_f32_16x16x32_f16(aA2, wfrag[gt][2], accA[gt], 0, 0, 0);  \
            accB[gt] = __builtin_amdgcn_mfma_f32_16x16x32_f16(aB2, wfrag[gt][2], accB[gt], 0, 0, 0);  \
        }                                                                              \
        _Pragma("unroll")                                                              \
        for (int gt = 0; gt < 4; ++gt) {                                               \
            accA[gt] = __builtin_amdgcn_mfma_f32_16x16x32_f16(aA3, wfrag[gt][3], accA[gt], 0, 0, 0);  \
            accB[gt] = __builtin_amdgcn_mfma_f32_16x16x32_f16(aB3, wfrag[gt][3], accB[gt], 0, 0, 0);  \
        }                                                                              \
        f16x8 axA = *(const f16x8*)&xf16[(T) + 1][col & 1][0];                         \
        f16x8 axB = *(const f16x8*)&xf16[(T) + 1][2 + (col & 1)][0];                   \
        _Pragma("unroll")                                                              \
        for (int gt = 0; gt < 4; ++gt) {                                               \
            accXA[gt] = __builtin_amdgcn_mfma_f32_16x16x32_f16(axA, wfrag[gt][4], zero, 0, 0, 0);     \
            accXB[gt] = __builtin_amdgcn_mfma_f32_16x16x32_f16(axB, wfrag[gt][4], zero, 0, 0, 0);     \
        }                                                                              \
        float z[4];                                                                    \
        _Pragma("unroll")                                                              \
        for (int gt = 0; gt < 4; ++gt) {                                               \
            float za = m1 ? accA[gt][1] : accA[gt][0];                                 \
            float zv = m1 ? accB[gt][1] : accB[gt][0];                                 \
            z[gt] = mG ? zv : za;                                                      \
        }                                                                              \
        float si = sig2(z[0]);                                                         \
        float sf = sig2(z[1]);                                                         \
        float tg = tanh2(z[2]);                                                        \
        float so = sig2(z[3]);                                                         \
        cc = sf * cc + si * tg;                                                        \
        float h = so * tanh2(cc * N2LOG2E);                                            \
        hbase[(NXT)*320 + woff] = (_Float16)h;                                         \
        __syncthreads();                                                               \
    }

    for (int t = 0; t < SEQ; t += 2) {
        ENC_STEP(t, 0, 1)
        ENC_STEP(t + 1, 1, 0)
    }
    #undef ENC_STEP
    // h_enc in buffer 0 of each group; c_enc = cc per lane (gb, u).

    // ---------------- decoder zbase (all 8 waves, scaled dec weights) ----------
    #pragma unroll
    for (int gt = 0; gt < 4; ++gt) {
        const int row = gt * HID + u;
        const float gs = GS[gt];
        #pragma unroll
        for (int kc = 0; kc < 4; ++kc) {
            const float* wr = dWhh + (size_t)row * HID + kc * 32 + grp * 8;
            f16x8 wf;
            #pragma unroll
            for (int e = 0; e < 8; ++e) wf[e] = (_Float16)(gs * wr[e]);
            wfrag[gt][kc] = wf;
        }
    }
    {
        f16x8 aA0 = *(const f16x8*)&hbA[0*80 + rbase];
        f16x8 aB0 = *(const f16x8*)&hbB[0*80 + rbase];
        f16x8 aA1 = *(const f16x8*)&hbA[1*80 + rbase];
        f16x8 aB1 = *(const f16x8*)&hbB[1*80 + rbase];
        f16x8 aA2 = *(const f16x8*)&hbA[2*80 + rbase];
        f16x8 aB2 = *(const f16x8*)&hbB[2*80 + rbase];
        f16x8 aA3 = *(const f16x8*)&hbA[3*80 + rbase];
        f16x8 aB3 = *(const f16x8*)&hbB[3*80 + rbase];
        #pragma unroll
        for (int gt = 0; gt < 4; ++gt) {
            float bd = GS[gt] * (dbih[gt * HID + u] + dbhh[gt * HID + u]);
            f32x4 aA = (f32x4){bd, bd, bd, bd};
            f32x4 aB = aA;
            aA = __builtin_amdgcn_mfma_f32_16x16x32_f16(aA0, wfrag[gt][0], aA, 0, 0, 0);
            aB = __builtin_amdgcn_mfma_f32_16x16x32_f16(aB0, wfrag[gt][0], aB, 0, 0, 0);
            aA = __builtin_amdgcn_mfma_f32_16x16x32_f16(aA1, wfrag[gt][1], aA, 0, 0, 0);
            aB = __builtin_amdgcn_mfma_f32_16x16x32_f16(aB1, wfrag[gt][1], aB, 0, 0, 0);
            aA = __builtin_amdgcn_mfma_f32_16x16x32_f16(aA2, wfrag[gt][2], aA, 0, 0, 0);
            aB = __builtin_amdgcn_mfma_f32_16x16x32_f16(aB2, wfrag[gt][2], aB, 0, 0, 0);
            aA = __builtin_amdgcn_mfma_f32_16x16x32_f16(aA3, wfrag[gt][3], aA, 0, 0, 0);
            aB = __builtin_amdgcn_mfma_f32_16x16x32_f16(aB3, wfrag[gt][3], aB, 0, 0, 0);
            float za = m1 ? aA[1] : aA[0];
            float zv = m1 ? aB[1] : aB[0];
            zbl[gt][gb][u] = mG ? zv : za;   // scaled z-base
        }
        cl[gb][u] = cc;
    }
    __syncthreads();

    // ---------------- decoder: 1 wave per batch row, no barriers ----------
    if (wave >= 4) return;
    {
        const int b = wave;
        const int u0 = lane, u1 = 64 + lane;
        float zb0[4], zb1[4], wd0[4][3], wd1[4][3];
        #pragma unroll
        for (int gt = 0; gt < 4; ++gt) {
            zb0[gt] = zbl[gt][b][u0];
            zb1[gt] = zbl[gt][b][u1];
            #pragma unroll
            for (int j = 0; j < 3; ++j) {
                wd0[gt][j] = GS[gt] * dWih[(size_t)(gt * HID + u0) * 3 + j];
                wd1[gt][j] = GS[gt] * dWih[(size_t)(gt * HID + u1) * 3 + j];
            }
        }
        const float c0 = cl[b][u0], c1 = cl[b][u1];
        float ow0[3], ow1[3];
        #pragma unroll
        for (int j = 0; j < 3; ++j) {
            ow0[j] = oW[j * HID + u0];
            ow1[j] = oW[j * HID + u1];
        }
        const float ob0 = ob[0], ob1 = ob[1], ob2 = ob[2];

        float y0 = 0.f, y1 = 0.f, y2 = 0.f;
        float* orow = out + (size_t)(b0 + b) * (TLEN * OUTD);

        for (int t = 0; t < TLEN; ++t) {
            float z0[4], z1[4];
            #pragma unroll
            for (int gt = 0; gt < 4; ++gt) {
                z0[gt] = zb0[gt] + wd0[gt][0] * y0 + wd0[gt][1] * y1 + wd0[gt][2] * y2;
                z1[gt] = zb1[gt] + wd1[gt][0] * y0 + wd1[gt][1] * y1 + wd1[gt][2] * y2;
            }
            float si0 = sig2(z0[0]), sf0 = sig2(z0[1]);
            float tg0 = tanh2(z0[2]), so0 = sig2(z0[3]);
            float si1 = sig2(z1[0]), sf1 = sig2(z1[1]);
            float tg1 = tanh2(z1[2]), so1 = sig2(z1[3]);
            float cd0 = sf0 * c0 + si0 * tg0;
            float cd1 = sf1 * c1 + si1 * tg1;
            float hd0 = so0 * tanh2(cd0 * N2LOG2E);
            float hd1 = so1 * tanh2(cd1 * N2LOG2E);
            float p0 = ow0[0] * hd0 + ow1[0] * hd1;
            float p1 = ow0[1] * hd0 + ow1[1] * hd1;
            float p2 = ow0[2] * hd0 + ow1[2] * hd1;
            y0 = wave_sum(p0) + ob0;
            y1 = wave_sum(p1) + ob1;
            y2 = wave_sum(p2) + ob2;
            if (lane < 3)
                orow[t * OUTD + lane] = (lane == 0) ? y0 : (lane == 1) ? y1 : y2;
        }
    }
}

extern "C" void kernel_launch(void* const* d_in, const int* in_sizes, int n_in,
                              void* d_out, int out_size, void* d_ws, size_t ws_size,
                              hipStream_t stream) {
    (void)in_sizes; (void)n_in; (void)d_ws; (void)ws_size; (void)out_size;
    enc_dec_kernel<<<256, 512, 0, stream>>>(
        (const float*)d_in[0],
        (const float*)d_in[1], (const float*)d_in[2],
        (const float*)d_in[3], (const float*)d_in[4],
        (const float*)d_in[5], (const float*)d_in[6],
        (const float*)d_in[7], (const float*)d_in[8],
        (const float*)d_in[9], (const float*)d_in[10],
        (float*)d_out);
}

// Round 13
// 247.112 us; speedup vs baseline: 1.4569x; 1.4569x over previous
//
#include <hip/hip_runtime.h>

#define SEQ 288
#define INP 7
#define HID 128
#define TLEN 288
#define OUTD 3
#define XW (SEQ * INP)   // 2016

typedef _Float16 f16x8 __attribute__((ext_vector_type(8)));
typedef float f32x4 __attribute__((ext_vector_type(4)));

#define NLOG2E  (-1.4426950408889634f)   // -log2(e)
#define N2LOG2E (-2.8853900817779268f)   // -2*log2(e)

__device__ __forceinline__ float exp2_fast(float x) {
#if __has_builtin(__builtin_amdgcn_exp2f)
    return __builtin_amdgcn_exp2f(x);
#else
    return __expf(x * 0.69314718056f);
#endif
}
__device__ __forceinline__ float sig2(float zp) {   // sigmoid, z pre-scaled by -log2e
    return __builtin_amdgcn_rcpf(1.0f + exp2_fast(zp));
}
__device__ __forceinline__ float tanh2(float zp) {  // tanh, z pre-scaled by -2log2e
    return 2.0f * __builtin_amdgcn_rcpf(1.0f + exp2_fast(zp)) - 1.0f;
}

// DPP-based full-wave (64) sum -> uniform scalar.
template<int CTRL, int RM>
__device__ __forceinline__ float dpp_add(float v) {
    int t = __builtin_amdgcn_update_dpp(0, __float_as_int(v), CTRL, RM, 0xF, true);
    return v + __int_as_float(t);
}
__device__ __forceinline__ float wave_sum(float v) {
    v = dpp_add<0xB1, 0xF>(v);
    v = dpp_add<0x4E, 0xF>(v);
    v = dpp_add<0x124, 0xF>(v);
    v = dpp_add<0x128, 0xF>(v);
    v = dpp_add<0x142, 0xA>(v);
    v = dpp_add<0x143, 0xC>(v);
    return __int_as_float(__builtin_amdgcn_readlane(__float_as_int(v), 63));
}

__global__ __launch_bounds__(512, 2)
void enc_dec_kernel(const float* __restrict__ x,
                    const float* __restrict__ eWih, const float* __restrict__ eWhh,
                    const float* __restrict__ ebih, const float* __restrict__ ebhh,
                    const float* __restrict__ dWih, const float* __restrict__ dWhh,
                    const float* __restrict__ dbih, const float* __restrict__ dbhh,
                    const float* __restrict__ oW,  const float* __restrict__ ob,
                    float* __restrict__ out)
{
    // h double-buffer, batch-packed: [dbuf][kc(4)][batch(4)][ke(40 pad)] f16.
    // A-reads are BATCH-MAJOR: A-row i <- batch i>>2, so lane L's own regs
    // hold its own batch; z = acc[0] directly (no select, no cross-lane).
    __shared__ __align__(16) _Float16 hbuf[2][4][4][40];
    // pre-converted x + constant-1 (bias rider): [t][b][8], j=7 == 1.0
    __shared__ __align__(16) _Float16 xf16[SEQ][4][8];
    __shared__ float zbl[4][4][HID];   // decoder zbase handoff [gate][b][u] (SCALED)
    __shared__ float cl[4][HID];       // c_enc handoff [b][u]

    const int tid  = threadIdx.x;
    const int wave = tid >> 6;
    const int lane = tid & 63;
    const int col  = lane & 15;        // A-row index / B n-col index
    const int grp  = lane >> 4;        // k-chunk 0..3; also this lane's batch row
    const int u    = wave * 16 + col;  // this lane's unit column
    const int bb   = grp;              // this lane's batch row
    const int b0   = blockIdx.x * 4;

    // gate scale factors: i,f,o -> -log2e ; g -> -2log2e
    const float GS[4] = {NLOG2E, NLOG2E, N2LOG2E, NLOG2E};

    // ---- prologue: zero hbuf, build xf16 ----
    {
        _Float16* hb = &hbuf[0][0][0][0];
        for (int i = tid; i < 2 * 4 * 4 * 40; i += 512) hb[i] = (_Float16)0.f;
    }
    for (int i = tid; i < 4 * XW; i += 512) {
        int b = i / XW, r = i % XW;
        int t = r / INP, j = r % INP;
        xf16[t][b][j] = (_Float16)x[(size_t)(b0 + b) * XW + r];
    }
    for (int i = tid; i < SEQ * 4; i += 512)
        xf16[i >> 2][i & 3][7] = (_Float16)1.0f;

    // ---- encoder weights as persistent B-fragments (PRE-SCALED) ----
    // kc 0..3: Whh (k = kc*32 + grp*8 + e); kc 4: Wih cols j<7, bias at j==7
    f16x8 wfrag[4][5];
    #pragma unroll
    for (int gt = 0; gt < 4; ++gt) {
        const int row = gt * HID + u;
        const float gs = GS[gt];
        #pragma unroll
        for (int kc = 0; kc < 4; ++kc) {
            const float* wr = eWhh + (size_t)row * HID + kc * 32 + grp * 8;
            f16x8 wf;
            #pragma unroll
            for (int e = 0; e < 8; ++e) wf[e] = (_Float16)(gs * wr[e]);
            wfrag[gt][kc] = wf;
        }
        {
            f16x8 wf;
            #pragma unroll
            for (int e = 0; e < 8; ++e) {
                int j = grp * 8 + e;
                float v = 0.f;
                if (j < INP)       v = eWih[(size_t)row * INP + j];
                else if (j == 7)   v = ebih[row] + ebhh[row];
                wf[e] = (_Float16)(gs * v);
            }
            wfrag[gt][4] = wf;
        }
    }

    __syncthreads();   // xf16 + hbuf ready

    float cc = 0.f;    // c state for this lane's (bb, u)
    const f32x4 zero = (f32x4){0.f, 0.f, 0.f, 0.f};

    // ---------------- encoder: 288 steps, unrolled x4 ----------------
    // Per 4-step group: ONE packed-x MFMA per gate gives zxp[gt], whose
    // reg dt = scaled (x_{T4+dt} @ Wih.T + bias) for this lane's (bb,u).
    // Packed A-row i = (batch i>>2, step-offset i&3).
    #define ENC_STEP(DT, CUR, NXT)                                                    \
    {                                                                                 \
        f16x8 af0 = *(const f16x8*)&hbuf[CUR][0][col >> 2][grp * 8];                  \
        f16x8 af1 = *(const f16x8*)&hbuf[CUR][1][col >> 2][grp * 8];                  \
        f16x8 af2 = *(const f16x8*)&hbuf[CUR][2][col >> 2][grp * 8];                  \
        f16x8 af3 = *(const f16x8*)&hbuf[CUR][3][col >> 2][grp * 8];                  \
        f32x4 acc[4];                                                                 \
        _Pragma("unroll")                                                             \
        for (int gt = 0; gt < 4; ++gt) {                                              \
            acc[gt] = __builtin_amdgcn_mfma_f32_16x16x32_f16(af0, wfrag[gt][0], zero,    0, 0, 0); \
            acc[gt] = __builtin_amdgcn_mfma_f32_16x16x32_f16(af1, wfrag[gt][1], acc[gt], 0, 0, 0); \
            acc[gt] = __builtin_amdgcn_mfma_f32_16x16x32_f16(af2, wfrag[gt][2], acc[gt], 0, 0, 0); \
            acc[gt] = __builtin_amdgcn_mfma_f32_16x16x32_f16(af3, wfrag[gt][3], acc[gt], 0, 0, 0); \
        }                                                                             \
        float si = sig2(acc[0][0] + zxp[0][DT]);                                      \
        float sf = sig2(acc[1][0] + zxp[1][DT]);                                      \
        float tg = tanh2(acc[2][0] + zxp[2][DT]);                                     \
        float so = sig2(acc[3][0] + zxp[3][DT]);                                      \
        cc = sf * cc + si * tg;                                                       \
        float h = so * tanh2(cc * N2LOG2E);                                           \
        hbuf[NXT][u >> 5][bb][u & 31] = (_Float16)h;                                  \
        __syncthreads();                                                              \
    }

    for (int t4 = 0; t4 < SEQ; t4 += 4) {
        f32x4 zxp[4];
        {
            f16x8 axp = *(const f16x8*)&xf16[t4 + (col & 3)][col >> 2][0];
            #pragma unroll
            for (int gt = 0; gt < 4; ++gt)
                zxp[gt] = __builtin_amdgcn_mfma_f32_16x16x32_f16(axp, wfrag[gt][4], zero, 0, 0, 0);
        }
        ENC_STEP(0, 0, 1)
        ENC_STEP(1, 1, 0)
        ENC_STEP(2, 0, 1)
        ENC_STEP(3, 1, 0)
    }
    #undef ENC_STEP
    // h_enc in hbuf[0]; c_enc = cc per lane (bb, u).

    // ---------------- decoder zbase (all 8 waves, scaled dec weights) ----------
    #pragma unroll
    for (int gt = 0; gt < 4; ++gt) {
        const int row = gt * HID + u;
        const float gs = GS[gt];
        #pragma unroll
        for (int kc = 0; kc < 4; ++kc) {
            const float* wr = dWhh + (size_t)row * HID + kc * 32 + grp * 8;
            f16x8 wf;
            #pragma unroll
            for (int e = 0; e < 8; ++e) wf[e] = (_Float16)(gs * wr[e]);
            wfrag[gt][kc] = wf;
        }
    }
    {
        f16x8 af0 = *(const f16x8*)&hbuf[0][0][col >> 2][grp * 8];
        f16x8 af1 = *(const f16x8*)&hbuf[0][1][col >> 2][grp * 8];
        f16x8 af2 = *(const f16x8*)&hbuf[0][2][col >> 2][grp * 8];
        f16x8 af3 = *(const f16x8*)&hbuf[0][3][col >> 2][grp * 8];
        #pragma unroll
        for (int gt = 0; gt < 4; ++gt) {
            float bd = GS[gt] * (dbih[gt * HID + u] + dbhh[gt * HID + u]);
            f32x4 acc = (f32x4){bd, bd, bd, bd};
            acc = __builtin_amdgcn_mfma_f32_16x16x32_f16(af0, wfrag[gt][0], acc, 0, 0, 0);
            acc = __builtin_amdgcn_mfma_f32_16x16x32_f16(af1, wfrag[gt][1], acc, 0, 0, 0);
            acc = __builtin_amdgcn_mfma_f32_16x16x32_f16(af2, wfrag[gt][2], acc, 0, 0, 0);
            acc = __builtin_amdgcn_mfma_f32_16x16x32_f16(af3, wfrag[gt][3], acc, 0, 0, 0);
            zbl[gt][bb][u] = acc[0];   // scaled z-base, own batch in reg 0
        }
        cl[bb][u] = cc;
    }
    __syncthreads();

    // ---------------- decoder: 1 wave per batch row, no barriers ----------
    if (wave >= 4) return;
    {
        const int b = wave;
        const int u0 = lane, u1 = 64 + lane;
        float zb0[4], zb1[4], wd0[4][3], wd1[4][3];
        #pragma unroll
        for (int gt = 0; gt < 4; ++gt) {
            zb0[gt] = zbl[gt][b][u0];
            zb1[gt] = zbl[gt][b][u1];
            #pragma unroll
            for (int j = 0; j < 3; ++j) {
                wd0[gt][j] = GS[gt] * dWih[(size_t)(gt * HID + u0) * 3 + j];
                wd1[gt][j] = GS[gt] * dWih[(size_t)(gt * HID + u1) * 3 + j];
            }
        }
        const float c0 = cl[b][u0], c1 = cl[b][u1];
        float ow0[3], ow1[3];
        #pragma unroll
        for (int j = 0; j < 3; ++j) {
            ow0[j] = oW[j * HID + u0];
            ow1[j] = oW[j * HID + u1];
        }
        const float ob0 = ob[0], ob1 = ob[1], ob2 = ob[2];

        float y0 = 0.f, y1 = 0.f, y2 = 0.f;
        float* orow = out + (size_t)(b0 + b) * (TLEN * OUTD);

        for (int t = 0; t < TLEN; ++t) {
            float z0[4], z1[4];
            #pragma unroll
            for (int gt = 0; gt < 4; ++gt) {
                z0[gt] = zb0[gt] + wd0[gt][0] * y0 + wd0[gt][1] * y1 + wd0[gt][2] * y2;
                z1[gt] = zb1[gt] + wd1[gt][0] * y0 + wd1[gt][1] * y1 + wd1[gt][2] * y2;
            }
            float si0 = sig2(z0[0]), sf0 = sig2(z0[1]);
            float tg0 = tanh2(z0[2]), so0 = sig2(z0[3]);
            float si1 = sig2(z1[0]), sf1 = sig2(z1[1]);
            float tg1 = tanh2(z1[2]), so1 = sig2(z1[3]);
            float cd0 = sf0 * c0 + si0 * tg0;
            float cd1 = sf1 * c1 + si1 * tg1;
            float hd0 = so0 * tanh2(cd0 * N2LOG2E);
            float hd1 = so1 * tanh2(cd1 * N2LOG2E);
            float p0 = ow0[0] * hd0 + ow1[0] * hd1;
            float p1 = ow0[1] * hd0 + ow1[1] * hd1;
            float p2 = ow0[2] * hd0 + ow1[2] * hd1;
            y0 = wave_sum(p0) + ob0;
            y1 = wave_sum(p1) + ob1;
            y2 = wave_sum(p2) + ob2;
            if (lane < 3)
                orow[t * OUTD + lane] = (lane == 0) ? y0 : (lane == 1) ? y1 : y2;
        }
    }
}

extern "C" void kernel_launch(void* const* d_in, const int* in_sizes, int n_in,
                              void* d_out, int out_size, void* d_ws, size_t ws_size,
                              hipStream_t stream) {
    (void)in_sizes; (void)n_in; (void)d_ws; (void)ws_size; (void)out_size;
    enc_dec_kernel<<<256, 512, 0, stream>>>(
        (const float*)d_in[0],
        (const float*)d_in[1], (const float*)d_in[2],
        (const float*)d_in[3], (const float*)d_in[4],
        (const float*)d_in[5], (const float*)d_in[6],
        (const float*)d_in[7], (const float*)d_in[8],
        (const float*)d_in[9], (const float*)d_in[10],
        (float*)d_out);
}